// Round 10
// baseline (1304.899 us; speedup 1.0000x reference)
//
#include <hip/hip_runtime.h>
#include <math.h>

#define DEV static __device__ __forceinline__

typedef __attribute__((ext_vector_type(8))) short bf16x8;
typedef __attribute__((ext_vector_type(4))) float f32x4;

DEV float gelu_exact(float x) {
    return 0.5f * x * (1.0f + erff(x * 0.70710678118654752f));
}

DEV short f2bf(float f) {
    union { float f; unsigned u; } v; v.f = f;
    unsigned r = v.u + 0x7FFF + ((v.u >> 16) & 1);  // round-to-nearest-even
    return (short)(r >> 16);
}

DEV float bf2f(unsigned short b) {
    union { unsigned u; float f; } v; v.u = ((unsigned)b) << 16;
    return v.f;
}

DEV unsigned pack2bf(float a, float b) {
    return ((unsigned)(unsigned short)f2bf(a)) | (((unsigned)(unsigned short)f2bf(b)) << 16);
}

DEV void gload_lds16(const void* g, void* lds) {
    __builtin_amdgcn_global_load_lds(
        (const __attribute__((address_space(1))) void*)g,
        (__attribute__((address_space(3))) void*)lds, 16, 0, 0);
}

// ---------------- conv1: (B,1,512,200) -> (B,8,512,25), k=15 stride=8 pad=7 ----------------
__global__ void conv1_kernel(const float* __restrict__ x, const float* __restrict__ w,
                             const float* __restrict__ bias, float* __restrict__ out) {
    int idx = blockIdx.x * blockDim.x + threadIdx.x;
    const int total = 8 * 8 * 512 * 25;
    if (idx >= total) return;
    int ow = idx % 25;
    int p  = (idx / 25) % 512;
    int oc = (idx / (25 * 512)) % 8;
    int b  = idx / (25 * 512 * 8);
    const float* xp = x + b * 512 * 200 + p * 200;
    const float* wp = w + oc * 15;
    float acc = bias[oc];
    int t0 = ow * 8 - 7;
#pragma unroll
    for (int k = 0; k < 15; k++) {
        int t = t0 + k;
        if (t >= 0 && t < 200) acc += wp[k] * xp[t];
    }
    out[idx] = acc;
}

// ---------------- conv 1x3 (pad 1) on (B,8,512,25) ----------------
__global__ void conv3x1_kernel(const float* __restrict__ in, const float* __restrict__ w,
                               const float* __restrict__ bias, float* __restrict__ out) {
    int idx = blockIdx.x * blockDim.x + threadIdx.x;
    const int total = 8 * 8 * 512 * 25;
    if (idx >= total) return;
    int ow = idx % 25;
    int p  = (idx / 25) % 512;
    int oc = (idx / 12800) & 7;
    int b  = idx / 102400;
    float acc = bias[oc];
#pragma unroll
    for (int ic = 0; ic < 8; ic++) {
        const float* ip = in + b * 102400 + ic * 12800 + p * 25;
        const float* wp = w + oc * 24 + ic * 3;
        if (ow > 0)  acc += wp[0] * ip[ow - 1];
        acc += wp[1] * ip[ow];
        if (ow < 24) acc += wp[2] * ip[ow + 1];
    }
    out[idx] = acc;
}

// ---------------- groupnorm ----------------
__global__ void gn_stats_kernel(const float* __restrict__ buf, float* __restrict__ stats) {
    int b = blockIdx.x >> 2, g = blockIdx.x & 3;
    const float* base = buf + b * 102400 + g * 2 * 12800;
    float s = 0.f, s2 = 0.f;
    for (int l = threadIdx.x; l < 25600; l += 256) {
        float v = base[l];
        s += v; s2 += v * v;
    }
    __shared__ float ss[256], ss2[256];
    ss[threadIdx.x] = s; ss2[threadIdx.x] = s2;
    __syncthreads();
    for (int o = 128; o; o >>= 1) {
        if (threadIdx.x < o) { ss[threadIdx.x] += ss[threadIdx.x + o]; ss2[threadIdx.x] += ss2[threadIdx.x + o]; }
        __syncthreads();
    }
    if (threadIdx.x == 0) {
        float m = ss[0] / 25600.f;
        float v = ss2[0] / 25600.f - m * m;
        stats[blockIdx.x * 2] = m;
        stats[blockIdx.x * 2 + 1] = v;
    }
}

__global__ void gn_apply_kernel(float* __restrict__ buf, const float* __restrict__ stats,
                                const float* __restrict__ g, const float* __restrict__ bb) {
    int idx = blockIdx.x * blockDim.x + threadIdx.x;
    if (idx >= 8 * 102400) return;
    int c = (idx / 12800) & 7;
    int b = idx / 102400;
    int grp = c >> 1;
    float m = stats[(b * 4 + grp) * 2];
    float v = stats[(b * 4 + grp) * 2 + 1];
    float val = (buf[idx] - m) * rsqrtf(v + 1e-5f) * g[c] + bb[c];
    buf[idx] = gelu_exact(val);
}

// ---------------- embed ----------------
__global__ void embed_kernel(const float* __restrict__ conv, const float* __restrict__ cls,
                             const float* __restrict__ pos, const float* __restrict__ te,
                             float* __restrict__ h) {
    int idx = blockIdx.x * blockDim.x + threadIdx.x;
    if (idx >= 8 * 513 * 200) return;
    int d = idx % 200;
    int n = (idx / 200) % 513;
    int b = idx / (200 * 513);
    float val;
    if (n == 0) {
        val = cls[d] + pos[d];
    } else {
        int p = n - 1;
        int t = d >> 3;
        int c = d & 7;
        val = conv[b * 102400 + c * 12800 + p * 25 + t];
        int ch = p >> 3, tw = p & 7;
        val += pos[(1 + ch) * 200 + d] + te[tw * 200 + d];
    }
    h[idx] = val;
}

// ---------------- weight convert+pad: fp32 [R][K] -> bf16 [R][KP] ----------------
__global__ void convpad_kernel(const float* __restrict__ src, short* __restrict__ dst,
                               int R, int K, int KP) {
    int idx = blockIdx.x * blockDim.x + threadIdx.x;
    if (idx >= R * KP) return;
    int r = idx / KP, c = idx % KP;
    dst[idx] = (c < K) ? f2bf(src[r * K + c]) : (short)0;
}

// ---------------- bias precompute via LDS table (16B stores) ----------------
__global__ __launch_bounds__(256) void bias_lds_kernel(const float* __restrict__ table,
                                                       const int* __restrict__ ridx,
                                                       short* __restrict__ bias) {
    __shared__ float tl[1908];
    const int qt = blockIdx.x, hh = blockIdx.y, d = blockIdx.z;
    const float* tab = table + d * 19080;
    for (int i = threadIdx.x; i < 1908; i += 256) tl[i] = tab[i * 10 + hh];
    __syncthreads();
    const int q0 = qt * 64;
    const int nrows = min(64, 513 - q0);
    short* obase = bias + ((size_t)d * 10 + hh) * 513 * 576;
    for (int lin = threadIdx.x; lin < nrows * 72; lin += 256) {
        int r = lin / 72, j = lin % 72;
        int q = q0 + r;
        const int* rp = ridx + q * 513;
        int k0 = j * 8;
        float v[8];
#pragma unroll
        for (int e = 0; e < 8; e++) {
            int k = k0 + e;
            v[e] = (k < 513) ? tl[rp[k]] : 0.f;
        }
        uint4 pk;
        pk.x = pack2bf(v[0], v[1]);
        pk.y = pack2bf(v[2], v[3]);
        pk.z = pack2bf(v[4], v[5]);
        pk.w = pack2bf(v[6], v[7]);
        *(uint4*)&obase[(size_t)q * 576 + k0] = pk;
    }
}

// ---------------- LN-fused bf16 MFMA GEMM: C = LN(H) @ W^T ----------------
// BM=64, BN=128, KP=256 (4 k-steps), 4 waves 2x2 (wave tile 32x64).
// Prologue: each wave row-LNs its 16 rows of H (fp32 [M][200]) into a static swizzled
// A-tile [64][256] bf16 (lane j owns cols 4j..4j+3; ds_write_b64), overlapping the W
// prefetch already in flight. W double-buffered with counted vmcnt (r9-proven pattern).
// EPI 2: Cb = bf16(gelu(acc+bias[n])), pad cols to NPout
// EPI 3: qkv scatter -> Qb (scaled), Kb, Vt
template <int EPI>
__global__ __launch_bounds__(256) void lngemm_bf(const float* __restrict__ H,
                                                 const short* __restrict__ W,
                                                 const float* __restrict__ lng,
                                                 const float* __restrict__ lnb,
                                                 short* __restrict__ Cb,
                                                 const float* __restrict__ bias,
                                                 int M, int N, int ldc, int NPout,
                                                 short* __restrict__ Qb = nullptr,
                                                 short* __restrict__ Kb = nullptr,
                                                 short* __restrict__ Vt = nullptr) {
    __shared__ __align__(16) short At[64 * 256];      // 32 KB, granule-XOR swizzled
    __shared__ __align__(16) short Ws[2][128 * 64];   // 2 x 16 KB

    const int tid = threadIdx.x;
    const int w = tid >> 6, l = tid & 63;
    const int wm = (w >> 1) * 32, wn = (w & 1) * 64;
    const int bm = blockIdx.y * 64, bn = blockIdx.x * 128;

    auto stageW = [&](int buf, int k0) {
#pragma unroll
        for (int it = 0; it < 4; it++) {
            int lin = it * 256 + tid;
            int row = lin >> 3, slot = lin & 7;
            int srcslot = slot ^ (row & 7);
            gload_lds16(W + (size_t)(bn + row) * 256 + k0 + srcslot * 8,
                        (char*)Ws[buf] + lin * 16);
        }
    };

    stageW(0, 0);  // W k-step 0 in flight during LN prologue

    // ---- LN prologue: wave w owns rows w*16 .. w*16+15 ----
    float4 gv = {0, 0, 0, 0}, bv = {0, 0, 0, 0};
    if (l < 50) {
        gv = *(const float4*)&lng[l * 4];
        bv = *(const float4*)&lnb[l * 4];
    }
    for (int rr = 0; rr < 16; rr++) {
        int row = w * 16 + rr;
        int gm = bm + row;
        float4 hv = {0, 0, 0, 0};
        if (gm < M && l < 50) hv = *(const float4*)&H[(size_t)gm * 200 + l * 4];
        float s = hv.x + hv.y + hv.z + hv.w;
        float q = hv.x * hv.x + hv.y * hv.y + hv.z * hv.z + hv.w * hv.w;
#pragma unroll
        for (int o = 32; o; o >>= 1) { s += __shfl_xor(s, o); q += __shfl_xor(q, o); }
        float mean = s * (1.f / 200.f);
        float var = q * (1.f / 200.f) - mean * mean;
        float rstd = rsqrtf(var + 1e-6f);
        float v0 = (l < 50) ? (hv.x - mean) * rstd * gv.x + bv.x : 0.f;
        float v1 = (l < 50) ? (hv.y - mean) * rstd * gv.y + bv.y : 0.f;
        float v2 = (l < 50) ? (hv.z - mean) * rstd * gv.z + bv.z : 0.f;
        float v3 = (l < 50) ? (hv.w - mean) * rstd * gv.w + bv.w : 0.f;
        uint2 pk;
        pk.x = pack2bf(v0, v1);
        pk.y = pack2bf(v2, v3);
        // logical bytes 8l..8l+7 of row -> swizzled granule (l>>1)^(row&7)
        *(uint2*)((char*)At + row * 512 + ((((l >> 1) ^ (row & 7)) << 4) | ((l & 1) * 8))) = pk;
    }
    asm volatile("s_waitcnt lgkmcnt(0)" ::: "memory");  // drain own ds_writes pre-barrier

    f32x4 acc[2][4] = {};
    int cur = 0;
#pragma unroll
    for (int kstep = 0; kstep < 4; kstep++) {
        if (kstep < 3) {
            stageW(cur ^ 1, (kstep + 1) * 64);
            asm volatile("s_waitcnt vmcnt(4)" ::: "memory");
        } else {
            asm volatile("s_waitcnt vmcnt(0)" ::: "memory");
        }
        __builtin_amdgcn_s_barrier();

        const char* Wc = (const char*)Ws[cur];
#pragma unroll
        for (int kk = 0; kk < 2; kk++) {
            const int kbyteW = kk * 64 + (l >> 4) * 16;
            const int g = kstep * 8 + kk * 4 + (l >> 4);  // A granule index 0..31
            bf16x8 af[2], bfr[4];
#pragma unroll
            for (int i = 0; i < 2; i++) {
                int r = wm + i * 16 + (l & 15);
                af[i] = *(const bf16x8*)((const char*)At + r * 512 + ((g ^ (r & 7)) << 4));
            }
#pragma unroll
            for (int j = 0; j < 4; j++) {
                int r = wn + j * 16 + (l & 15);
                bfr[j] = *(const bf16x8*)(Wc + r * 128 + (kbyteW ^ ((r & 7) << 4)));
            }
#pragma unroll
            for (int i = 0; i < 2; i++)
#pragma unroll
                for (int j = 0; j < 4; j++)
                    acc[i][j] = __builtin_amdgcn_mfma_f32_16x16x32_bf16(af[i], bfr[j], acc[i][j], 0, 0, 0);
        }
        __builtin_amdgcn_s_barrier();
        cur ^= 1;
    }

    const int col0 = bn + wn + (l & 15);
    const int rbase = (l >> 4) * 4;
#pragma unroll
    for (int i = 0; i < 2; i++) {
#pragma unroll
        for (int r = 0; r < 4; r++) {
            int gm = bm + wm + i * 16 + rbase + r;
            if (gm >= M) continue;
#pragma unroll
            for (int j = 0; j < 4; j++) {
                int gn = col0 + j * 16;
                float v = acc[i][j][r];
                if (EPI == 2) {
                    if (gn < NPout)
                        Cb[(size_t)gm * ldc + gn] = (gn < N) ? f2bf(gelu_exact(v + bias[gn])) : (short)0;
                } else {  // EPI 3: qkv scatter
                    if (gn < 600) {
                        int bb2 = gm / 513, n = gm - bb2 * 513;
                        if (gn < 200) {
                            int hq = gn / 20, dq = gn - hq * 20;
                            Qb[((size_t)(bb2 * 10 + hq) * 576 + n) * 32 + dq] =
                                f2bf(v * 0.22360679774997896f);
                        } else if (gn < 400) {
                            int gk = gn - 200, hk = gk / 20, dk = gk - hk * 20;
                            Kb[((size_t)(bb2 * 10 + hk) * 576 + n) * 32 + dk] = f2bf(v);
                        } else {
                            int gv2 = gn - 400, hv2 = gv2 / 20, dv2 = gv2 - hv2 * 20;
                            Vt[((size_t)(bb2 * 10 + hv2) * 32 + dv2) * 576 + n] = f2bf(v);
                        }
                    }
                }
            }
        }
    }
}

// ---------------- bf16 MFMA GEMM, double-buffered K-loop (proj / fc2) ----------------
// EPI 1: Cf = res + gamma[n]*(acc+bias[n])
template <int EPI, int BM, int BN>
__global__ __launch_bounds__(256) void gemm_bf(const short* __restrict__ A,
                                               const short* __restrict__ W,
                                               float* __restrict__ Cf,
                                               const float* __restrict__ res,
                                               const float* __restrict__ bias,
                                               const float* __restrict__ gamma,
                                               int M, int N, int KP, int ldc) {
    constexpr int WM = BM / 2, WN = BN / 2;
    constexpr int AM = WM / 16, BNr = WN / 16;
    constexpr int LOADS = (BM + BN) / 32;
    __shared__ __align__(16) short Ss[2][(BM + BN) * 64];

    const int tid = threadIdx.x;
    const int w = tid >> 6, l = tid & 63;
    const int wm = (w >> 1) * WM, wn = (w & 1) * WN;
    const int bm = blockIdx.y * BM, bn = blockIdx.x * BN;

    f32x4 acc[AM][BNr] = {};

    auto stage = [&](int buf, int k0) {
#pragma unroll
        for (int it = 0; it < LOADS; it++) {
            int lin = it * 256 + tid;
            int row = lin >> 3, slot = lin & 7;
            int srcslot = slot ^ (row & 7);
            const short* g;
            if (it * 32 < BM) {
                g = A + (size_t)(bm + row) * KP + k0 + srcslot * 8;
            } else {
                g = W + (size_t)(bn + row - BM) * KP + k0 + srcslot * 8;
            }
            gload_lds16(g, (char*)Ss[buf] + lin * 16);
        }
    };

    const int nk = KP >> 6;
    stage(0, 0);
    int cur = 0;
    for (int kstep = 0; kstep < nk; kstep++) {
        if (kstep + 1 < nk) {
            stage(cur ^ 1, (kstep + 1) << 6);
            if constexpr (LOADS == 6) asm volatile("s_waitcnt vmcnt(6)" ::: "memory");
            else                      asm volatile("s_waitcnt vmcnt(4)" ::: "memory");
        } else {
            asm volatile("s_waitcnt vmcnt(0)" ::: "memory");
        }
        __builtin_amdgcn_s_barrier();

        const char* Sc = (const char*)Ss[cur];
#pragma unroll
        for (int kk = 0; kk < 2; kk++) {
            const int kbyte = kk * 64 + (l >> 4) * 16;
            bf16x8 af[AM], bfr[BNr];
#pragma unroll
            for (int i = 0; i < AM; i++) {
                int r = wm + i * 16 + (l & 15);
                af[i] = *(const bf16x8*)(Sc + r * 128 + (kbyte ^ ((r & 7) << 4)));
            }
#pragma unroll
            for (int j = 0; j < BNr; j++) {
                int r = BM + wn + j * 16 + (l & 15);
                bfr[j] = *(const bf16x8*)(Sc + r * 128 + (kbyte ^ ((r & 7) << 4)));
            }
#pragma unroll
            for (int i = 0; i < AM; i++)
#pragma unroll
                for (int j = 0; j < BNr; j++)
                    acc[i][j] = __builtin_amdgcn_mfma_f32_16x16x32_bf16(af[i], bfr[j], acc[i][j], 0, 0, 0);
        }
        __builtin_amdgcn_s_barrier();
        cur ^= 1;
    }

    const int col0 = bn + wn + (l & 15);
    const int rbase = (l >> 4) * 4;
#pragma unroll
    for (int i = 0; i < AM; i++) {
#pragma unroll
        for (int r = 0; r < 4; r++) {
            int gm = bm + wm + i * 16 + rbase + r;
            if (gm >= M) continue;
#pragma unroll
            for (int j = 0; j < BNr; j++) {
                int gn = col0 + j * 16;
                if (gn < N)
                    Cf[(size_t)gm * ldc + gn] =
                        res[(size_t)gm * ldc + gn] + gamma[gn] * (acc[i][j][r] + bias[gn]);
            }
        }
    }
}

// ---------------- MFMA flash attention, double-buffered staging ----------------
__global__ __launch_bounds__(256) void attn_mfma2(const short* __restrict__ Qb,
                                                  const short* __restrict__ Kb,
                                                  const short* __restrict__ Vt,
                                                  const short* __restrict__ biasb,
                                                  short* __restrict__ ob) {
    __shared__ __align__(16) short Klds[2][64 * 32];
    __shared__ __align__(16) short Vlds[2][32 * 64];
    __shared__ __align__(16) short Blds[2][64 * 64];
    __shared__ __align__(16) short Pl[4 * 16 * 72];

    const int orig = blockIdx.x;
    const int wg = (orig & 7) * 90 + (orig >> 3);   // XCD-chunked bijection (720 = 8*90)
    const int hh = wg / 72;
    const int rem = wg % 72;
    const int qt = rem >> 3, b = rem & 7;

    const int t = threadIdx.x, wave = t >> 6, l = t & 63;
    const int lq = l & 15, hi = l >> 4;
    const int n = qt * 64 + wave * 16 + lq;
    const int nc = min(n, 512);

    const size_t bh = (size_t)(b * 10 + hh);
    const short* Kbase = Kb + bh * 576 * 32;
    const short* Vbase = Vt + bh * 32 * 576;
    const short* Bbase = biasb + (size_t)hh * 513 * 576;

    bf16x8 qf = *(const bf16x8*)&Qb[(bh * 576 + nc) * 32 + hi * 8];

    const int krow = t >> 2, kch = t & 3;
    const short* ksrc = Kbase + (size_t)krow * 32 + (kch ^ ((krow >> 2) & 3)) * 8;
    const int vrow = t >> 3, vch = t & 7;
    const short* vsrc = Vbase + (size_t)vrow * 576 + (vch ^ (vrow & 7)) * 8;
    const int b0row = t >> 3, b0ch = t & 7;
    const short* bsrc0 = Bbase + (size_t)min(qt * 64 + b0row, 512) * 576 + (b0ch ^ (b0row & 7)) * 8;
    const int b1row = 32 + (t >> 3);
    const short* bsrc1 = Bbase + (size_t)min(qt * 64 + b1row, 512) * 576 + (b0ch ^ (b1row & 7)) * 8;

    float mrun = -1e30f, lsum = 0.f;
    f32x4 oacc0 = {}, oacc1 = {};
    const f32x4 zero4 = {};

    gload_lds16(ksrc, (char*)Klds[0] + t * 16);
    gload_lds16(vsrc, (char*)Vlds[0] + t * 16);
    gload_lds16(bsrc0, (char*)Blds[0] + t * 16);
    gload_lds16(bsrc1, (char*)Blds[0] + 4096 + t * 16);

    int cur = 0;
    for (int kt = 0; kt < 9; kt++) {
        const int koff = kt * 64;
        if (kt < 8) {
            const int knext = koff + 64;
            gload_lds16(ksrc + (size_t)knext * 32, (char*)Klds[cur ^ 1] + t * 16);
            gload_lds16(vsrc + knext, (char*)Vlds[cur ^ 1] + t * 16);
            gload_lds16(bsrc0 + knext, (char*)Blds[cur ^ 1] + t * 16);
            gload_lds16(bsrc1 + knext, (char*)Blds[cur ^ 1] + 4096 + t * 16);
            asm volatile("s_waitcnt vmcnt(4)" ::: "memory");
        } else {
            asm volatile("s_waitcnt vmcnt(0)" ::: "memory");
        }
        __builtin_amdgcn_s_barrier();

        const short* Kc = Klds[cur];
        const short* Vc = Vlds[cur];
        const short* Bc = Blds[cur];

        f32x4 s[4];
#pragma unroll
        for (int c = 0; c < 4; c++) {
            int r = c * 16 + lq;
            bf16x8 kf = *(const bf16x8*)((const char*)Kc + r * 64 + ((hi ^ ((lq >> 2) & 3)) << 4));
            s[c] = __builtin_amdgcn_mfma_f32_16x16x32_bf16(kf, qf, zero4, 0, 0, 0);
        }

        const int brow = wave * 16 + lq;
        float sv[4][4];
        float tm = -1e30f;
#pragma unroll
        for (int c = 0; c < 4; c++) {
            uint2 bl = *(const uint2*)((const char*)Bc + brow * 128 +
                                       (((2 * c + (hi >> 1)) ^ (lq & 7)) << 4) + (hi & 1) * 8);
            float bv[4] = { bf2f((unsigned short)(bl.x & 0xFFFF)), bf2f((unsigned short)(bl.x >> 16)),
                            bf2f((unsigned short)(bl.y & 0xFFFF)), bf2f((unsigned short)(bl.y >> 16)) };
            int kglob = koff + c * 16 + hi * 4;
#pragma unroll
            for (int r = 0; r < 4; r++) {
                float val = s[c][r] + bv[r];
                if (kglob + r > 512) val = -1e30f;
                sv[c][r] = val;
                tm = fmaxf(tm, val);
            }
        }
        tm = fmaxf(tm, __shfl_xor(tm, 16));
        tm = fmaxf(tm, __shfl_xor(tm, 32));
        float mnew = fmaxf(mrun, tm);
        float resc = __expf(mrun - mnew);
        mrun = mnew;

        float ts = 0.f;
#pragma unroll
        for (int c = 0; c < 4; c++) {
            float p0 = __expf(sv[c][0] - mnew);
            float p1 = __expf(sv[c][1] - mnew);
            float p2 = __expf(sv[c][2] - mnew);
            float p3 = __expf(sv[c][3] - mnew);
            ts += (p0 + p1) + (p2 + p3);
            uint2 pk;
            pk.x = pack2bf(p0, p1);
            pk.y = pack2bf(p2, p3);
            *(uint2*)&Pl[wave * 1152 + lq * 72 + c * 16 + hi * 4] = pk;
        }
        ts += __shfl_xor(ts, 16);
        ts += __shfl_xor(ts, 32);
        lsum = lsum * resc + ts;
        oacc0 *= resc;
        oacc1 *= resc;

#pragma unroll
        for (int kc = 0; kc < 2; kc++) {
            bf16x8 pf = *(const bf16x8*)&Pl[wave * 1152 + lq * 72 + kc * 32 + hi * 8];
            bf16x8 vf0 = *(const bf16x8*)((const char*)Vc + lq * 128 +
                                          (((kc * 4 + hi) ^ (lq & 7)) << 4));
            bf16x8 vf1 = *(const bf16x8*)((const char*)Vc + (16 + lq) * 128 +
                                          (((kc * 4 + hi) ^ (lq & 7)) << 4));
            oacc0 = __builtin_amdgcn_mfma_f32_16x16x32_bf16(vf0, pf, oacc0, 0, 0, 0);
            oacc1 = __builtin_amdgcn_mfma_f32_16x16x32_bf16(vf1, pf, oacc1, 0, 0, 0);
        }

        __builtin_amdgcn_s_barrier();
        cur ^= 1;
    }

    if (n < 513) {
        float inv = 1.f / lsum;
        short* op = ob + (size_t)(b * 513 + n) * 256 + hh * 20;
        {
            uint2 pk;
            pk.x = pack2bf(oacc0[0] * inv, oacc0[1] * inv);
            pk.y = pack2bf(oacc0[2] * inv, oacc0[3] * inv);
            *(uint2*)&op[hi * 4] = pk;
        }
        if (hi == 0) {
            uint2 pk;
            pk.x = pack2bf(oacc1[0] * inv, oacc1[1] * inv);
            pk.y = pack2bf(oacc1[2] * inv, oacc1[3] * inv);
            *(uint2*)&op[16] = pk;
        }
    }
}

// ---------------- final: mean-pool patches -> LN -> head (200 -> 4) ----------------
__global__ __launch_bounds__(256) void final_kernel(const float* __restrict__ h,
                                                    const float* __restrict__ g,
                                                    const float* __restrict__ bb,
                                                    const float* __restrict__ hw,
                                                    const float* __restrict__ hb,
                                                    float* __restrict__ out) {
    __shared__ float pool[256];
    __shared__ float red[256];
    int b = blockIdx.x, t = threadIdx.x;
    float s = 0.f;
    if (t < 200) {
        const float* hp = h + b * 513 * 200 + 200 + t;
        for (int p = 0; p < 512; p++) s += hp[p * 200];
        s *= (1.f / 512.f);
    }
    pool[t] = (t < 200) ? s : 0.f;
    red[t] = pool[t];
    __syncthreads();
    for (int o = 128; o; o >>= 1) {
        if (t < o) red[t] += red[t + o];
        __syncthreads();
    }
    float mean = red[0] / 200.f;
    __syncthreads();
    float dv = (t < 200) ? (pool[t] - mean) : 0.f;
    red[t] = dv * dv;
    __syncthreads();
    for (int o = 128; o; o >>= 1) {
        if (t < o) red[t] += red[t + o];
        __syncthreads();
    }
    float var = red[0] / 200.f;
    float rstd = rsqrtf(var + 1e-6f);
    __syncthreads();
    if (t < 200) pool[t] = (pool[t] - mean) * rstd * g[t] + bb[t];
    __syncthreads();
    if (t < 4) {
        float acc = hb[t];
        for (int d2 = 0; d2 < 200; d2++) acc += pool[d2] * hw[t * 200 + d2];
        out[b * 4 + t] = acc;
    }
}

extern "C" void kernel_launch(void* const* d_in, const int* in_sizes, int n_in,
                              void* d_out, int out_size, void* d_ws, size_t ws_size,
                              hipStream_t stream) {
    const float* x        = (const float*)d_in[0];
    const float* conv1_w  = (const float*)d_in[1];
    const float* conv1_b  = (const float*)d_in[2];
    const float* gn1_g    = (const float*)d_in[3];
    const float* gn1_b    = (const float*)d_in[4];
    const float* conv2_w  = (const float*)d_in[5];
    const float* conv2_b  = (const float*)d_in[6];
    const float* gn2_g    = (const float*)d_in[7];
    const float* gn2_b    = (const float*)d_in[8];
    const float* conv3_w  = (const float*)d_in[9];
    const float* conv3_b  = (const float*)d_in[10];
    const float* gn3_g    = (const float*)d_in[11];
    const float* gn3_b    = (const float*)d_in[12];
    const float* cls_tok  = (const float*)d_in[13];
    const float* pos_emb  = (const float*)d_in[14];
    const float* time_emb = (const float*)d_in[15];
    const float* ln1_g    = (const float*)d_in[16];
    const float* ln1_b    = (const float*)d_in[17];
    const float* qkv_w    = (const float*)d_in[18];
    const float* rel_tab  = (const float*)d_in[19];
    const float* proj_w   = (const float*)d_in[20];
    const float* proj_b   = (const float*)d_in[21];
    const float* gamma1   = (const float*)d_in[22];
    const float* ln2_g    = (const float*)d_in[23];
    const float* ln2_b    = (const float*)d_in[24];
    const float* fc1_w    = (const float*)d_in[25];
    const float* fc1_b    = (const float*)d_in[26];
    const float* fc2_w    = (const float*)d_in[27];
    const float* fc2_b    = (const float*)d_in[28];
    const float* gamma2   = (const float*)d_in[29];
    const float* fcn_g    = (const float*)d_in[30];
    const float* fcn_b    = (const float*)d_in[31];
    const float* head_w   = (const float*)d_in[32];
    const float* head_b   = (const float*)d_in[33];
    const int*   rel_idx  = (const int*)d_in[34];

    // ---- workspace layout (bytes), total ~100 MB ----
    char* p = (char*)d_ws;
    float* h    = (float*)p; p += 3283200;          // 8*513*200 f32
    char* qreg = p;                                  // multi-phase region
    float* c1   = (float*)qreg;
    float* c2   = c1 + 819200;
    short* Qb   = (short*)qreg;                     // [8][10][576][32]
    short* Kb   = Qb + 1474560;
    short* Vt   = Kb + 1474560;                     // [8][10][32][576]
    short* mlp  = (short*)qreg;                     // [4104][832] (MLP phase)
    p += 9849600;
    short* ob   = (short*)p; p += 2101248;          // 4104*256 bf16
    short* wqkv = (short*)p; p += 3686400;
    short* wproj= (short*)p; p += 1228800;
    short* wfc1 = (short*)p; p += 4915200;
    short* wfc2 = (short*)p; p += 3993600;
    short* biasb= (short*)p; p += 12 * 5909760;     // [12][10][513][576] bf16 = 70.9 MB
    float* stats= (float*)p;

    // ---- upfront precompute ----
    convpad_kernel<<<(7200 * 256 + 255) / 256, 256, 0, stream>>>(qkv_w, wqkv, 7200, 200, 256);
    convpad_kernel<<<(2400 * 256 + 255) / 256, 256, 0, stream>>>(proj_w, wproj, 2400, 200, 256);
    convpad_kernel<<<(9600 * 256 + 255) / 256, 256, 0, stream>>>(fc1_w, wfc1, 9600, 200, 256);
    convpad_kernel<<<(2400 * 832 + 255) / 256, 256, 0, stream>>>(fc2_w, wfc2, 2400, 800, 832);
    bias_lds_kernel<<<dim3(9, 10, 12), 256, 0, stream>>>(rel_tab, rel_idx, biasb);
    hipMemsetAsync(ob, 0, 2101248, stream);

    // ---- patch embed ----
    conv1_kernel<<<3200, 256, 0, stream>>>(x, conv1_w, conv1_b, c1);
    gn_stats_kernel<<<32, 256, 0, stream>>>(c1, stats);
    gn_apply_kernel<<<3200, 256, 0, stream>>>(c1, stats, gn1_g, gn1_b);
    conv3x1_kernel<<<3200, 256, 0, stream>>>(c1, conv2_w, conv2_b, c2);
    gn_stats_kernel<<<32, 256, 0, stream>>>(c2, stats);
    gn_apply_kernel<<<3200, 256, 0, stream>>>(c2, stats, gn2_g, gn2_b);
    conv3x1_kernel<<<3200, 256, 0, stream>>>(c2, conv3_w, conv3_b, c1);
    gn_stats_kernel<<<32, 256, 0, stream>>>(c1, stats);
    gn_apply_kernel<<<3200, 256, 0, stream>>>(c1, stats, gn3_g, gn3_b);
    embed_kernel<<<(820800 + 255) / 256, 256, 0, stream>>>(c1, cls_tok, pos_emb, time_emb, h);

    hipMemsetAsync(Qb, 0, 3 * 1474560 * 2, stream);  // zero QKV pad regions (post conv phase)

    // ---- transformer layers (LN fused into qkv / fc1 prologues) ----
    for (int d = 0; d < 12; d++) {
        lngemm_bf<3><<<dim3(5, 65), 256, 0, stream>>>(h, wqkv + d * 153600,
                                                      ln1_g + d * 200, ln1_b + d * 200,
                                                      nullptr, nullptr,
                                                      4104, 600, 0, 0, Qb, Kb, Vt);
        attn_mfma2<<<720, 256, 0, stream>>>(Qb, Kb, Vt, biasb + (size_t)d * 2954880, ob);
        gemm_bf<1, 64, 64><<<dim3(4, 65), 256, 0, stream>>>(ob, wproj + d * 51200, h,
                                                            h, proj_b + d * 200, gamma1 + d * 200,
                                                            4104, 200, 256, 200);
        lngemm_bf<2><<<dim3(7, 65), 256, 0, stream>>>(h, wfc1 + d * 204800,
                                                      ln2_g + d * 200, ln2_b + d * 200,
                                                      mlp, fc1_b + d * 800,
                                                      4104, 800, 832, 832);
        gemm_bf<1, 64, 64><<<dim3(4, 65), 256, 0, stream>>>(mlp, wfc2 + d * 166400, h,
                                                            h, fc2_b + d * 200, gamma2 + d * 200,
                                                            4104, 200, 832, 200);
    }

    // ---- pool + head ----
    final_kernel<<<8, 256, 0, stream>>>(h, fcn_g, fcn_b, head_w, head_b, (float*)d_out);
}

// Round 11
// 1091.581 us; speedup vs baseline: 1.1954x; 1.1954x over previous
//
#include <hip/hip_runtime.h>
#include <math.h>

#define DEV static __device__ __forceinline__

typedef __attribute__((ext_vector_type(8))) short bf16x8;
typedef __attribute__((ext_vector_type(4))) float f32x4;

DEV float gelu_exact(float x) {
    return 0.5f * x * (1.0f + erff(x * 0.70710678118654752f));
}

DEV short f2bf(float f) {
    union { float f; unsigned u; } v; v.f = f;
    unsigned r = v.u + 0x7FFF + ((v.u >> 16) & 1);  // round-to-nearest-even
    return (short)(r >> 16);
}

DEV float bf2f(unsigned short b) {
    union { unsigned u; float f; } v; v.u = ((unsigned)b) << 16;
    return v.f;
}

DEV unsigned pack2bf(float a, float b) {
    return ((unsigned)(unsigned short)f2bf(a)) | (((unsigned)(unsigned short)f2bf(b)) << 16);
}

DEV void gload_lds16(const void* g, void* lds) {
    __builtin_amdgcn_global_load_lds(
        (const __attribute__((address_space(1))) void*)g,
        (__attribute__((address_space(3))) void*)lds, 16, 0, 0);
}

// ---------------- conv1: (B,1,512,200) -> (B,8,512,25), k=15 stride=8 pad=7 ----------------
__global__ void conv1_kernel(const float* __restrict__ x, const float* __restrict__ w,
                             const float* __restrict__ bias, float* __restrict__ out) {
    int idx = blockIdx.x * blockDim.x + threadIdx.x;
    const int total = 8 * 8 * 512 * 25;
    if (idx >= total) return;
    int ow = idx % 25;
    int p  = (idx / 25) % 512;
    int oc = (idx / (25 * 512)) % 8;
    int b  = idx / (25 * 512 * 8);
    const float* xp = x + b * 512 * 200 + p * 200;
    const float* wp = w + oc * 15;
    float acc = bias[oc];
    int t0 = ow * 8 - 7;
#pragma unroll
    for (int k = 0; k < 15; k++) {
        int t = t0 + k;
        if (t >= 0 && t < 200) acc += wp[k] * xp[t];
    }
    out[idx] = acc;
}

// ---------------- conv 1x3 (pad 1) on (B,8,512,25) ----------------
__global__ void conv3x1_kernel(const float* __restrict__ in, const float* __restrict__ w,
                               const float* __restrict__ bias, float* __restrict__ out) {
    int idx = blockIdx.x * blockDim.x + threadIdx.x;
    const int total = 8 * 8 * 512 * 25;
    if (idx >= total) return;
    int ow = idx % 25;
    int p  = (idx / 25) % 512;
    int oc = (idx / 12800) & 7;
    int b  = idx / 102400;
    float acc = bias[oc];
#pragma unroll
    for (int ic = 0; ic < 8; ic++) {
        const float* ip = in + b * 102400 + ic * 12800 + p * 25;
        const float* wp = w + oc * 24 + ic * 3;
        if (ow > 0)  acc += wp[0] * ip[ow - 1];
        acc += wp[1] * ip[ow];
        if (ow < 24) acc += wp[2] * ip[ow + 1];
    }
    out[idx] = acc;
}

// ---------------- groupnorm ----------------
__global__ void gn_stats_kernel(const float* __restrict__ buf, float* __restrict__ stats) {
    int b = blockIdx.x >> 2, g = blockIdx.x & 3;
    const float* base = buf + b * 102400 + g * 2 * 12800;
    float s = 0.f, s2 = 0.f;
    for (int l = threadIdx.x; l < 25600; l += 256) {
        float v = base[l];
        s += v; s2 += v * v;
    }
    __shared__ float ss[256], ss2[256];
    ss[threadIdx.x] = s; ss2[threadIdx.x] = s2;
    __syncthreads();
    for (int o = 128; o; o >>= 1) {
        if (threadIdx.x < o) { ss[threadIdx.x] += ss[threadIdx.x + o]; ss2[threadIdx.x] += ss2[threadIdx.x + o]; }
        __syncthreads();
    }
    if (threadIdx.x == 0) {
        float m = ss[0] / 25600.f;
        float v = ss2[0] / 25600.f - m * m;
        stats[blockIdx.x * 2] = m;
        stats[blockIdx.x * 2 + 1] = v;
    }
}

__global__ void gn_apply_kernel(float* __restrict__ buf, const float* __restrict__ stats,
                                const float* __restrict__ g, const float* __restrict__ bb) {
    int idx = blockIdx.x * blockDim.x + threadIdx.x;
    if (idx >= 8 * 102400) return;
    int c = (idx / 12800) & 7;
    int b = idx / 102400;
    int grp = c >> 1;
    float m = stats[(b * 4 + grp) * 2];
    float v = stats[(b * 4 + grp) * 2 + 1];
    float val = (buf[idx] - m) * rsqrtf(v + 1e-5f) * g[c] + bb[c];
    buf[idx] = gelu_exact(val);
}

// ---------------- embed ----------------
__global__ void embed_kernel(const float* __restrict__ conv, const float* __restrict__ cls,
                             const float* __restrict__ pos, const float* __restrict__ te,
                             float* __restrict__ h) {
    int idx = blockIdx.x * blockDim.x + threadIdx.x;
    if (idx >= 8 * 513 * 200) return;
    int d = idx % 200;
    int n = (idx / 200) % 513;
    int b = idx / (200 * 513);
    float val;
    if (n == 0) {
        val = cls[d] + pos[d];
    } else {
        int p = n - 1;
        int t = d >> 3;
        int c = d & 7;
        val = conv[b * 102400 + c * 12800 + p * 25 + t];
        int ch = p >> 3, tw = p & 7;
        val += pos[(1 + ch) * 200 + d] + te[tw * 200 + d];
    }
    h[idx] = val;
}

// ---------------- weight convert+pad: fp32 [R][K] -> bf16 [R][KP] ----------------
__global__ void convpad_kernel(const float* __restrict__ src, short* __restrict__ dst,
                               int R, int K, int KP) {
    int idx = blockIdx.x * blockDim.x + threadIdx.x;
    if (idx >= R * KP) return;
    int r = idx / KP, c = idx % KP;
    dst[idx] = (c < K) ? f2bf(src[r * K + c]) : (short)0;
}

// ---------------- bias precompute via LDS table (uint2 stores, unroll-2 for MLP) --------
__global__ __launch_bounds__(256) void bias_lds_kernel(const float* __restrict__ table,
                                                       const int* __restrict__ ridx,
                                                       short* __restrict__ bias) {
    __shared__ float tl[1908];
    const int qt = blockIdx.x, hh = blockIdx.y, d = blockIdx.z;
    const float* tab = table + d * 19080;
    for (int i = threadIdx.x; i < 1908; i += 256) tl[i] = tab[i * 10 + hh];
    __syncthreads();
    const int q0 = qt * 64;
    const int nrows = min(64, 513 - q0);
    short* obase = bias + ((size_t)d * 10 + hh) * 513 * 576;
#pragma unroll 2
    for (int lin = threadIdx.x; lin < nrows * 144; lin += 256) {
        int r = lin / 144, j = lin % 144;
        int q = q0 + r;
        const int* rp = ridx + q * 513;
        int k0 = j * 4;
        float v[4];
#pragma unroll
        for (int e = 0; e < 4; e++) {
            int k = k0 + e;
            v[e] = (k < 513) ? tl[rp[k]] : 0.f;
        }
        uint2 pk;
        pk.x = pack2bf(v[0], v[1]);
        pk.y = pack2bf(v[2], v[3]);
        *(uint2*)&obase[(size_t)q * 576 + k0] = pk;
    }
}

// ---------------- LayerNorm over D=200; 4 rows per 256-thr block (one wave/row) ----------
__global__ __launch_bounds__(256) void ln_kernel(const float* __restrict__ in,
                                                 const float* __restrict__ g,
                                                 const float* __restrict__ b,
                                                 short* __restrict__ out) {
    int row = blockIdx.x * 4 + (threadIdx.x >> 6);
    int lane = threadIdx.x & 63;
    const float* x = in + (size_t)row * 200;
    float v[4];
    float s = 0.f;
#pragma unroll
    for (int i = 0; i < 4; i++) {
        int d = lane + i * 64;
        v[i] = (d < 200) ? x[d] : 0.f;
        s += v[i];
    }
#pragma unroll
    for (int o = 32; o; o >>= 1) s += __shfl_xor(s, o);
    float mean = s * (1.f / 200.f);
    float s2 = 0.f;
#pragma unroll
    for (int i = 0; i < 4; i++) {
        int d = lane + i * 64;
        float dv = (d < 200) ? (v[i] - mean) : 0.f;
        s2 += dv * dv;
    }
#pragma unroll
    for (int o = 32; o; o >>= 1) s2 += __shfl_xor(s2, o);
    float rstd = rsqrtf(s2 * (1.f / 200.f) + 1e-6f);
#pragma unroll
    for (int i = 0; i < 4; i++) {
        int d = lane + i * 64;
        float val = (d < 200) ? (v[i] - mean) * rstd * g[d] + b[d] : 0.f;
        out[(size_t)row * 256 + d] = f2bf(val);
    }
}

// ---------------- bf16 MFMA GEMM, double-buffered K-loop ----------------
// BM x BN block tile, BK=64, 4 waves 2x2. Counted vmcnt (never 0 mid-loop).
// EPI 0: Cf = acc (fp32)
// EPI 1: Cf = res + gamma[n]*(acc+bias[n])
// EPI 2: Cb = bf16(gelu(acc+bias[n])), zero pad cols N..NPout
// EPI 3: qkv scatter -> Qb[b][h][576][32] (scaled), Kb same, Vt[b][h][32][576]
template <int EPI, int BM, int BN>
__global__ __launch_bounds__(256) void gemm_bf(const short* __restrict__ A,
                                               const short* __restrict__ W,
                                               float* __restrict__ Cf,
                                               short* __restrict__ Cb,
                                               const float* __restrict__ res,
                                               const float* __restrict__ bias,
                                               const float* __restrict__ gamma,
                                               int M, int N, int KP, int ldc, int NPout,
                                               short* __restrict__ Qb = nullptr,
                                               short* __restrict__ Kb = nullptr,
                                               short* __restrict__ Vt = nullptr) {
    constexpr int WM = BM / 2, WN = BN / 2;
    constexpr int AM = WM / 16, BNr = WN / 16;
    constexpr int LOADS = (BM + BN) / 32;   // gloads per thread per k-step
    __shared__ __align__(16) short Ss[2][(BM + BN) * 64];

    const int tid = threadIdx.x;
    const int w = tid >> 6, l = tid & 63;
    const int wm = (w >> 1) * WM, wn = (w & 1) * WN;
    const int bm = blockIdx.y * BM, bn = blockIdx.x * BN;

    f32x4 acc[AM][BNr] = {};

    auto stage = [&](int buf, int k0) {
#pragma unroll
        for (int it = 0; it < LOADS; it++) {
            int lin = it * 256 + tid;
            int row = lin >> 3, slot = lin & 7;
            int srcslot = slot ^ (row & 7);
            const short* g;
            if (it * 32 < BM) {
                g = A + (size_t)(bm + row) * KP + k0 + srcslot * 8;
            } else {
                g = W + (size_t)(bn + row - BM) * KP + k0 + srcslot * 8;
            }
            gload_lds16(g, (char*)Ss[buf] + lin * 16);
        }
    };

    const int nk = KP >> 6;
    stage(0, 0);
    int cur = 0;
    for (int kstep = 0; kstep < nk; kstep++) {
        if (kstep + 1 < nk) {
            stage(cur ^ 1, (kstep + 1) << 6);
            if constexpr (LOADS == 6) asm volatile("s_waitcnt vmcnt(6)" ::: "memory");
            else                      asm volatile("s_waitcnt vmcnt(4)" ::: "memory");
        } else {
            asm volatile("s_waitcnt vmcnt(0)" ::: "memory");
        }
        __builtin_amdgcn_s_barrier();

        const char* Sc = (const char*)Ss[cur];
#pragma unroll
        for (int kk = 0; kk < 2; kk++) {
            const int kbyte = kk * 64 + (l >> 4) * 16;
            bf16x8 af[AM], bfr[BNr];
#pragma unroll
            for (int i = 0; i < AM; i++) {
                int r = wm + i * 16 + (l & 15);
                af[i] = *(const bf16x8*)(Sc + r * 128 + (kbyte ^ ((r & 7) << 4)));
            }
#pragma unroll
            for (int j = 0; j < BNr; j++) {
                int r = BM + wn + j * 16 + (l & 15);
                bfr[j] = *(const bf16x8*)(Sc + r * 128 + (kbyte ^ ((r & 7) << 4)));
            }
#pragma unroll
            for (int i = 0; i < AM; i++)
#pragma unroll
                for (int j = 0; j < BNr; j++)
                    acc[i][j] = __builtin_amdgcn_mfma_f32_16x16x32_bf16(af[i], bfr[j], acc[i][j], 0, 0, 0);
        }
        __builtin_amdgcn_s_barrier();  // all waves done reading Ss[cur] before overwrite
        cur ^= 1;
    }

    const int col0 = bn + wn + (l & 15);
    const int rbase = (l >> 4) * 4;
#pragma unroll
    for (int i = 0; i < AM; i++) {
#pragma unroll
        for (int r = 0; r < 4; r++) {
            int gm = bm + wm + i * 16 + rbase + r;
            if (gm >= M) continue;
#pragma unroll
            for (int j = 0; j < BNr; j++) {
                int gn = col0 + j * 16;
                float v = acc[i][j][r];
                if (EPI == 0) {
                    if (gn < N) Cf[(size_t)gm * ldc + gn] = v;
                } else if (EPI == 1) {
                    if (gn < N) Cf[(size_t)gm * ldc + gn] =
                        res[(size_t)gm * ldc + gn] + gamma[gn] * (v + bias[gn]);
                } else if (EPI == 2) {
                    if (gn < NPout)
                        Cb[(size_t)gm * ldc + gn] = (gn < N) ? f2bf(gelu_exact(v + bias[gn])) : (short)0;
                } else {  // EPI 3: qkv scatter
                    if (gn < 600) {
                        int bb2 = gm / 513, n = gm - bb2 * 513;
                        if (gn < 200) {
                            int hq = gn / 20, dq = gn - hq * 20;
                            Qb[((size_t)(bb2 * 10 + hq) * 576 + n) * 32 + dq] =
                                f2bf(v * 0.22360679774997896f);
                        } else if (gn < 400) {
                            int gk = gn - 200, hk = gk / 20, dk = gk - hk * 20;
                            Kb[((size_t)(bb2 * 10 + hk) * 576 + n) * 32 + dk] = f2bf(v);
                        } else {
                            int gv = gn - 400, hv = gv / 20, dv2 = gv - hv * 20;
                            Vt[((size_t)(bb2 * 10 + hv) * 32 + dv2) * 576 + n] = f2bf(v);
                        }
                    }
                }
            }
        }
    }
}

// ---------------- MFMA flash attention, double-buffered staging + setprio ----------------
__global__ __launch_bounds__(256) void attn_mfma2(const short* __restrict__ Qb,
                                                  const short* __restrict__ Kb,
                                                  const short* __restrict__ Vt,
                                                  const short* __restrict__ biasb,
                                                  short* __restrict__ ob) {
    __shared__ __align__(16) short Klds[2][64 * 32];
    __shared__ __align__(16) short Vlds[2][32 * 64];
    __shared__ __align__(16) short Blds[2][64 * 64];
    __shared__ __align__(16) short Pl[4 * 16 * 72];

    const int orig = blockIdx.x;
    const int wg = (orig & 7) * 90 + (orig >> 3);   // XCD-chunked bijection (720 = 8*90)
    const int hh = wg / 72;
    const int rem = wg % 72;
    const int qt = rem >> 3, b = rem & 7;

    const int t = threadIdx.x, wave = t >> 6, l = t & 63;
    const int lq = l & 15, hi = l >> 4;
    const int n = qt * 64 + wave * 16 + lq;
    const int nc = min(n, 512);

    const size_t bh = (size_t)(b * 10 + hh);
    const short* Kbase = Kb + bh * 576 * 32;
    const short* Vbase = Vt + bh * 32 * 576;
    const short* Bbase = biasb + (size_t)hh * 513 * 576;

    bf16x8 qf = *(const bf16x8*)&Qb[(bh * 576 + nc) * 32 + hi * 8];

    const int krow = t >> 2, kch = t & 3;
    const short* ksrc = Kbase + (size_t)krow * 32 + (kch ^ ((krow >> 2) & 3)) * 8;
    const int vrow = t >> 3, vch = t & 7;
    const short* vsrc = Vbase + (size_t)vrow * 576 + (vch ^ (vrow & 7)) * 8;
    const int b0row = t >> 3, b0ch = t & 7;
    const short* bsrc0 = Bbase + (size_t)min(qt * 64 + b0row, 512) * 576 + (b0ch ^ (b0row & 7)) * 8;
    const int b1row = 32 + (t >> 3);
    const short* bsrc1 = Bbase + (size_t)min(qt * 64 + b1row, 512) * 576 + (b0ch ^ (b1row & 7)) * 8;

    float mrun = -1e30f, lsum = 0.f;
    f32x4 oacc0 = {}, oacc1 = {};
    const f32x4 zero4 = {};

    gload_lds16(ksrc, (char*)Klds[0] + t * 16);
    gload_lds16(vsrc, (char*)Vlds[0] + t * 16);
    gload_lds16(bsrc0, (char*)Blds[0] + t * 16);
    gload_lds16(bsrc1, (char*)Blds[0] + 4096 + t * 16);

    int cur = 0;
    for (int kt = 0; kt < 9; kt++) {
        const int koff = kt * 64;
        if (kt < 8) {
            const int knext = koff + 64;
            gload_lds16(ksrc + (size_t)knext * 32, (char*)Klds[cur ^ 1] + t * 16);
            gload_lds16(vsrc + knext, (char*)Vlds[cur ^ 1] + t * 16);
            gload_lds16(bsrc0 + knext, (char*)Blds[cur ^ 1] + t * 16);
            gload_lds16(bsrc1 + knext, (char*)Blds[cur ^ 1] + 4096 + t * 16);
            asm volatile("s_waitcnt vmcnt(4)" ::: "memory");
        } else {
            asm volatile("s_waitcnt vmcnt(0)" ::: "memory");
        }
        __builtin_amdgcn_s_barrier();

        const short* Kc = Klds[cur];
        const short* Vc = Vlds[cur];
        const short* Bc = Blds[cur];

        f32x4 s[4];
        __builtin_amdgcn_s_setprio(1);
#pragma unroll
        for (int c = 0; c < 4; c++) {
            int r = c * 16 + lq;
            bf16x8 kf = *(const bf16x8*)((const char*)Kc + r * 64 + ((hi ^ ((lq >> 2) & 3)) << 4));
            s[c] = __builtin_amdgcn_mfma_f32_16x16x32_bf16(kf, qf, zero4, 0, 0, 0);
        }
        __builtin_amdgcn_s_setprio(0);

        const int brow = wave * 16 + lq;
        float sv[4][4];
        float tm = -1e30f;
#pragma unroll
        for (int c = 0; c < 4; c++) {
            uint2 bl = *(const uint2*)((const char*)Bc + brow * 128 +
                                       (((2 * c + (hi >> 1)) ^ (lq & 7)) << 4) + (hi & 1) * 8);
            float bv[4] = { bf2f((unsigned short)(bl.x & 0xFFFF)), bf2f((unsigned short)(bl.x >> 16)),
                            bf2f((unsigned short)(bl.y & 0xFFFF)), bf2f((unsigned short)(bl.y >> 16)) };
            int kglob = koff + c * 16 + hi * 4;
#pragma unroll
            for (int r = 0; r < 4; r++) {
                float val = s[c][r] + bv[r];
                if (kglob + r > 512) val = -1e30f;
                sv[c][r] = val;
                tm = fmaxf(tm, val);
            }
        }
        tm = fmaxf(tm, __shfl_xor(tm, 16));
        tm = fmaxf(tm, __shfl_xor(tm, 32));
        float mnew = fmaxf(mrun, tm);
        float resc = __expf(mrun - mnew);
        mrun = mnew;

        float ts = 0.f;
#pragma unroll
        for (int c = 0; c < 4; c++) {
            float p0 = __expf(sv[c][0] - mnew);
            float p1 = __expf(sv[c][1] - mnew);
            float p2 = __expf(sv[c][2] - mnew);
            float p3 = __expf(sv[c][3] - mnew);
            ts += (p0 + p1) + (p2 + p3);
            uint2 pk;
            pk.x = pack2bf(p0, p1);
            pk.y = pack2bf(p2, p3);
            *(uint2*)&Pl[wave * 1152 + lq * 72 + c * 16 + hi * 4] = pk;
        }
        ts += __shfl_xor(ts, 16);
        ts += __shfl_xor(ts, 32);
        lsum = lsum * resc + ts;
        oacc0 *= resc;
        oacc1 *= resc;

        __builtin_amdgcn_s_setprio(1);
#pragma unroll
        for (int kc = 0; kc < 2; kc++) {
            bf16x8 pf = *(const bf16x8*)&Pl[wave * 1152 + lq * 72 + kc * 32 + hi * 8];
            bf16x8 vf0 = *(const bf16x8*)((const char*)Vc + lq * 128 +
                                          (((kc * 4 + hi) ^ (lq & 7)) << 4));
            bf16x8 vf1 = *(const bf16x8*)((const char*)Vc + (16 + lq) * 128 +
                                          (((kc * 4 + hi) ^ (lq & 7)) << 4));
            oacc0 = __builtin_amdgcn_mfma_f32_16x16x32_bf16(vf0, pf, oacc0, 0, 0, 0);
            oacc1 = __builtin_amdgcn_mfma_f32_16x16x32_bf16(vf1, pf, oacc1, 0, 0, 0);
        }
        __builtin_amdgcn_s_setprio(0);

        __builtin_amdgcn_s_barrier();
        cur ^= 1;
    }

    if (n < 513) {
        float inv = 1.f / lsum;
        short* op = ob + (size_t)(b * 513 + n) * 256 + hh * 20;
        {
            uint2 pk;
            pk.x = pack2bf(oacc0[0] * inv, oacc0[1] * inv);
            pk.y = pack2bf(oacc0[2] * inv, oacc0[3] * inv);
            *(uint2*)&op[hi * 4] = pk;
        }
        if (hi == 0) {
            uint2 pk;
            pk.x = pack2bf(oacc1[0] * inv, oacc1[1] * inv);
            pk.y = pack2bf(oacc1[2] * inv, oacc1[3] * inv);
            *(uint2*)&op[16] = pk;
        }
    }
}

// ---------------- final: mean-pool patches -> LN -> head (200 -> 4) ----------------
__global__ __launch_bounds__(256) void final_kernel(const float* __restrict__ h,
                                                    const float* __restrict__ g,
                                                    const float* __restrict__ bb,
                                                    const float* __restrict__ hw,
                                                    const float* __restrict__ hb,
                                                    float* __restrict__ out) {
    __shared__ float pool[256];
    __shared__ float red[256];
    int b = blockIdx.x, t = threadIdx.x;
    float s = 0.f;
    if (t < 200) {
        const float* hp = h + b * 513 * 200 + 200 + t;
        for (int p = 0; p < 512; p++) s += hp[p * 200];
        s *= (1.f / 512.f);
    }
    pool[t] = (t < 200) ? s : 0.f;
    red[t] = pool[t];
    __syncthreads();
    for (int o = 128; o; o >>= 1) {
        if (t < o) red[t] += red[t + o];
        __syncthreads();
    }
    float mean = red[0] / 200.f;
    __syncthreads();
    float dv = (t < 200) ? (pool[t] - mean) : 0.f;
    red[t] = dv * dv;
    __syncthreads();
    for (int o = 128; o; o >>= 1) {
        if (t < o) red[t] += red[t + o];
        __syncthreads();
    }
    float var = red[0] / 200.f;
    float rstd = rsqrtf(var + 1e-6f);
    __syncthreads();
    if (t < 200) pool[t] = (pool[t] - mean) * rstd * g[t] + bb[t];
    __syncthreads();
    if (t < 4) {
        float acc = hb[t];
        for (int d2 = 0; d2 < 200; d2++) acc += pool[d2] * hw[t * 200 + d2];
        out[b * 4 + t] = acc;
    }
}

extern "C" void kernel_launch(void* const* d_in, const int* in_sizes, int n_in,
                              void* d_out, int out_size, void* d_ws, size_t ws_size,
                              hipStream_t stream) {
    const float* x        = (const float*)d_in[0];
    const float* conv1_w  = (const float*)d_in[1];
    const float* conv1_b  = (const float*)d_in[2];
    const float* gn1_g    = (const float*)d_in[3];
    const float* gn1_b    = (const float*)d_in[4];
    const float* conv2_w  = (const float*)d_in[5];
    const float* conv2_b  = (const float*)d_in[6];
    const float* gn2_g    = (const float*)d_in[7];
    const float* gn2_b    = (const float*)d_in[8];
    const float* conv3_w  = (const float*)d_in[9];
    const float* conv3_b  = (const float*)d_in[10];
    const float* gn3_g    = (const float*)d_in[11];
    const float* gn3_b    = (const float*)d_in[12];
    const float* cls_tok  = (const float*)d_in[13];
    const float* pos_emb  = (const float*)d_in[14];
    const float* time_emb = (const float*)d_in[15];
    const float* ln1_g    = (const float*)d_in[16];
    const float* ln1_b    = (const float*)d_in[17];
    const float* qkv_w    = (const float*)d_in[18];
    const float* rel_tab  = (const float*)d_in[19];
    const float* proj_w   = (const float*)d_in[20];
    const float* proj_b   = (const float*)d_in[21];
    const float* gamma1   = (const float*)d_in[22];
    const float* ln2_g    = (const float*)d_in[23];
    const float* ln2_b    = (const float*)d_in[24];
    const float* fc1_w    = (const float*)d_in[25];
    const float* fc1_b    = (const float*)d_in[26];
    const float* fc2_w    = (const float*)d_in[27];
    const float* fc2_b    = (const float*)d_in[28];
    const float* gamma2   = (const float*)d_in[29];
    const float* fcn_g    = (const float*)d_in[30];
    const float* fcn_b    = (const float*)d_in[31];
    const float* head_w   = (const float*)d_in[32];
    const float* head_b   = (const float*)d_in[33];
    const int*   rel_idx  = (const int*)d_in[34];

    // ---- workspace layout (bytes), total ~102 MB ----
    char* p = (char*)d_ws;
    float* h    = (float*)p; p += 3283200;          // 8*513*200 f32
    char* qreg = p;                                  // multi-phase region
    float* c1   = (float*)qreg;
    float* c2   = c1 + 819200;
    short* Qb   = (short*)qreg;                     // [8][10][576][32]
    short* Kb   = Qb + 1474560;
    short* Vt   = Kb + 1474560;                     // [8][10][32][576]
    short* mlp  = (short*)qreg;                     // [4104][832] (MLP phase)
    p += 9849600;
    short* y    = (short*)p; p += 2101248;          // 4104*256 bf16
    short* ob   = (short*)p; p += 2101248;          // 4104*256 bf16
    short* wqkv = (short*)p; p += 3686400;
    short* wproj= (short*)p; p += 1228800;
    short* wfc1 = (short*)p; p += 4915200;
    short* wfc2 = (short*)p; p += 3993600;
    short* biasb= (short*)p; p += 12 * 5909760;     // [12][10][513][576] bf16 = 70.9 MB
    float* stats= (float*)p;

    // ---- upfront precompute ----
    convpad_kernel<<<(7200 * 256 + 255) / 256, 256, 0, stream>>>(qkv_w, wqkv, 7200, 200, 256);
    convpad_kernel<<<(2400 * 256 + 255) / 256, 256, 0, stream>>>(proj_w, wproj, 2400, 200, 256);
    convpad_kernel<<<(9600 * 256 + 255) / 256, 256, 0, stream>>>(fc1_w, wfc1, 9600, 200, 256);
    convpad_kernel<<<(2400 * 832 + 255) / 256, 256, 0, stream>>>(fc2_w, wfc2, 2400, 800, 832);
    bias_lds_kernel<<<dim3(9, 10, 12), 256, 0, stream>>>(rel_tab, rel_idx, biasb);
    hipMemsetAsync(ob, 0, 2101248, stream);

    // ---- patch embed ----
    conv1_kernel<<<3200, 256, 0, stream>>>(x, conv1_w, conv1_b, c1);
    gn_stats_kernel<<<32, 256, 0, stream>>>(c1, stats);
    gn_apply_kernel<<<3200, 256, 0, stream>>>(c1, stats, gn1_g, gn1_b);
    conv3x1_kernel<<<3200, 256, 0, stream>>>(c1, conv2_w, conv2_b, c2);
    gn_stats_kernel<<<32, 256, 0, stream>>>(c2, stats);
    gn_apply_kernel<<<3200, 256, 0, stream>>>(c2, stats, gn2_g, gn2_b);
    conv3x1_kernel<<<3200, 256, 0, stream>>>(c2, conv3_w, conv3_b, c1);
    gn_stats_kernel<<<32, 256, 0, stream>>>(c1, stats);
    gn_apply_kernel<<<3200, 256, 0, stream>>>(c1, stats, gn3_g, gn3_b);
    embed_kernel<<<(820800 + 255) / 256, 256, 0, stream>>>(c1, cls_tok, pos_emb, time_emb, h);

    hipMemsetAsync(Qb, 0, 3 * 1474560 * 2, stream);  // zero QKV pad regions (post conv phase)

    // ---- transformer layers ----
    for (int d = 0; d < 12; d++) {
        ln_kernel<<<1026, 256, 0, stream>>>(h, ln1_g + d * 200, ln1_b + d * 200, y);
        gemm_bf<3, 64, 128><<<dim3(5, 65), 256, 0, stream>>>(y, wqkv + d * 153600,
                                                             nullptr, nullptr, nullptr, nullptr, nullptr,
                                                             4104, 600, 256, 0, 0, Qb, Kb, Vt);
        attn_mfma2<<<720, 256, 0, stream>>>(Qb, Kb, Vt, biasb + (size_t)d * 2954880, ob);
        gemm_bf<1, 64, 64><<<dim3(4, 65), 256, 0, stream>>>(ob, wproj + d * 51200, h, nullptr,
                                                            h, proj_b + d * 200, gamma1 + d * 200,
                                                            4104, 200, 256, 200, 0);
        ln_kernel<<<1026, 256, 0, stream>>>(h, ln2_g + d * 200, ln2_b + d * 200, y);
        gemm_bf<2, 64, 128><<<dim3(7, 65), 256, 0, stream>>>(y, wfc1 + d * 204800, nullptr, mlp,
                                                             nullptr, fc1_b + d * 800, nullptr,
                                                             4104, 800, 256, 832, 832);
        gemm_bf<1, 64, 64><<<dim3(4, 65), 256, 0, stream>>>(mlp, wfc2 + d * 166400, h, nullptr,
                                                            h, fc2_b + d * 200, gamma2 + d * 200,
                                                            4104, 200, 832, 200, 0);
    }

    // ---- pool + head ----
    final_kernel<<<8, 256, 0, stream>>>(h, fcn_g, fcn_b, head_w, head_b, (float*)d_out);
}

// Round 12
// 1042.877 us; speedup vs baseline: 1.2512x; 1.0467x over previous
//
#include <hip/hip_runtime.h>
#include <math.h>

#define DEV static __device__ __forceinline__

typedef __attribute__((ext_vector_type(8))) short bf16x8;
typedef __attribute__((ext_vector_type(4))) float f32x4;

DEV float gelu_exact(float x) {
    return 0.5f * x * (1.0f + erff(x * 0.70710678118654752f));
}

DEV short f2bf(float f) {
    union { float f; unsigned u; } v; v.f = f;
    unsigned r = v.u + 0x7FFF + ((v.u >> 16) & 1);  // round-to-nearest-even
    return (short)(r >> 16);
}

DEV float bf2f(unsigned short b) {
    union { unsigned u; float f; } v; v.u = ((unsigned)b) << 16;
    return v.f;
}

DEV unsigned pack2bf(float a, float b) {
    return ((unsigned)(unsigned short)f2bf(a)) | (((unsigned)(unsigned short)f2bf(b)) << 16);
}

DEV void gload_lds16(const void* g, void* lds) {
    __builtin_amdgcn_global_load_lds(
        (const __attribute__((address_space(1))) void*)g,
        (__attribute__((address_space(3))) void*)lds, 16, 0, 0);
}

// ---------------- conv1: (B,1,512,200) -> (B,8,512,25), k=15 stride=8 pad=7 ----------------
__global__ void conv1_kernel(const float* __restrict__ x, const float* __restrict__ w,
                             const float* __restrict__ bias, float* __restrict__ out) {
    int idx = blockIdx.x * blockDim.x + threadIdx.x;
    const int total = 8 * 8 * 512 * 25;
    if (idx >= total) return;
    int ow = idx % 25;
    int p  = (idx / 25) % 512;
    int oc = (idx / (25 * 512)) % 8;
    int b  = idx / (25 * 512 * 8);
    const float* xp = x + b * 512 * 200 + p * 200;
    const float* wp = w + oc * 15;
    float acc = bias[oc];
    int t0 = ow * 8 - 7;
#pragma unroll
    for (int k = 0; k < 15; k++) {
        int t = t0 + k;
        if (t >= 0 && t < 200) acc += wp[k] * xp[t];
    }
    out[idx] = acc;
}

// ---------------- conv 1x3 (pad 1) on (B,8,512,25) ----------------
__global__ void conv3x1_kernel(const float* __restrict__ in, const float* __restrict__ w,
                               const float* __restrict__ bias, float* __restrict__ out) {
    int idx = blockIdx.x * blockDim.x + threadIdx.x;
    const int total = 8 * 8 * 512 * 25;
    if (idx >= total) return;
    int ow = idx % 25;
    int p  = (idx / 25) % 512;
    int oc = (idx / 12800) & 7;
    int b  = idx / 102400;
    float acc = bias[oc];
#pragma unroll
    for (int ic = 0; ic < 8; ic++) {
        const float* ip = in + b * 102400 + ic * 12800 + p * 25;
        const float* wp = w + oc * 24 + ic * 3;
        if (ow > 0)  acc += wp[0] * ip[ow - 1];
        acc += wp[1] * ip[ow];
        if (ow < 24) acc += wp[2] * ip[ow + 1];
    }
    out[idx] = acc;
}

// ---------------- groupnorm ----------------
__global__ void gn_stats_kernel(const float* __restrict__ buf, float* __restrict__ stats) {
    int b = blockIdx.x >> 2, g = blockIdx.x & 3;
    const float* base = buf + b * 102400 + g * 2 * 12800;
    float s = 0.f, s2 = 0.f;
    for (int l = threadIdx.x; l < 25600; l += 256) {
        float v = base[l];
        s += v; s2 += v * v;
    }
    __shared__ float ss[256], ss2[256];
    ss[threadIdx.x] = s; ss2[threadIdx.x] = s2;
    __syncthreads();
    for (int o = 128; o; o >>= 1) {
        if (threadIdx.x < o) { ss[threadIdx.x] += ss[threadIdx.x + o]; ss2[threadIdx.x] += ss2[threadIdx.x + o]; }
        __syncthreads();
    }
    if (threadIdx.x == 0) {
        float m = ss[0] / 25600.f;
        float v = ss2[0] / 25600.f - m * m;
        stats[blockIdx.x * 2] = m;
        stats[blockIdx.x * 2 + 1] = v;
    }
}

__global__ void gn_apply_kernel(float* __restrict__ buf, const float* __restrict__ stats,
                                const float* __restrict__ g, const float* __restrict__ bb) {
    int idx = blockIdx.x * blockDim.x + threadIdx.x;
    if (idx >= 8 * 102400) return;
    int c = (idx / 12800) & 7;
    int b = idx / 102400;
    int grp = c >> 1;
    float m = stats[(b * 4 + grp) * 2];
    float v = stats[(b * 4 + grp) * 2 + 1];
    float val = (buf[idx] - m) * rsqrtf(v + 1e-5f) * g[c] + bb[c];
    buf[idx] = gelu_exact(val);
}

// ---------------- embed ----------------
__global__ void embed_kernel(const float* __restrict__ conv, const float* __restrict__ cls,
                             const float* __restrict__ pos, const float* __restrict__ te,
                             float* __restrict__ h) {
    int idx = blockIdx.x * blockDim.x + threadIdx.x;
    if (idx >= 8 * 513 * 200) return;
    int d = idx % 200;
    int n = (idx / 200) % 513;
    int b = idx / (200 * 513);
    float val;
    if (n == 0) {
        val = cls[d] + pos[d];
    } else {
        int p = n - 1;
        int t = d >> 3;
        int c = d & 7;
        val = conv[b * 102400 + c * 12800 + p * 25 + t];
        int ch = p >> 3, tw = p & 7;
        val += pos[(1 + ch) * 200 + d] + te[tw * 200 + d];
    }
    h[idx] = val;
}

// ---------------- weight convert+pad (vec4): fp32 [R][K] -> bf16 [R][KP] ----------------
__global__ void convpad_kernel(const float* __restrict__ src, short* __restrict__ dst,
                               int R, int K, int KP) {
    int idx = blockIdx.x * blockDim.x + threadIdx.x;
    int total = R * (KP >> 2);
    if (idx >= total) return;
    int r = idx / (KP >> 2);
    int c4 = (idx - r * (KP >> 2)) << 2;
    short4 o;
    if (c4 + 3 < K) {
        float4 f = *(const float4*)&src[(size_t)r * K + c4];
        o.x = f2bf(f.x); o.y = f2bf(f.y); o.z = f2bf(f.z); o.w = f2bf(f.w);
    } else {
        o.x = (c4 + 0 < K) ? f2bf(src[(size_t)r * K + c4 + 0]) : (short)0;
        o.y = (c4 + 1 < K) ? f2bf(src[(size_t)r * K + c4 + 1]) : (short)0;
        o.z = (c4 + 2 < K) ? f2bf(src[(size_t)r * K + c4 + 2]) : (short)0;
        o.w = (c4 + 3 < K) ? f2bf(src[(size_t)r * K + c4 + 3]) : (short)0;
    }
    *(short4*)&dst[(size_t)r * KP + c4] = o;
}

// ---------------- bias precompute via LDS table (uint2 stores, unroll 2) ----------------
__global__ __launch_bounds__(256) void bias_lds_kernel(const float* __restrict__ table,
                                                       const int* __restrict__ ridx,
                                                       short* __restrict__ bias) {
    __shared__ float tl[1908];
    const int qt = blockIdx.x, hh = blockIdx.y, d = blockIdx.z;
    const float* tab = table + d * 19080;
    for (int i = threadIdx.x; i < 1908; i += 256) tl[i] = tab[i * 10 + hh];
    __syncthreads();
    const int q0 = qt * 64;
    const int nrows = min(64, 513 - q0);
    short* obase = bias + ((size_t)d * 10 + hh) * 513 * 576;
#pragma unroll 2
    for (int lin = threadIdx.x; lin < nrows * 144; lin += 256) {
        int r = lin / 144, j = lin % 144;
        int q = q0 + r;
        const int* rp = ridx + q * 513;
        int k0 = j * 4;
        float v[4];
#pragma unroll
        for (int e = 0; e < 4; e++) {
            int k = k0 + e;
            v[e] = (k < 513) ? tl[rp[k]] : 0.f;
        }
        uint2 pk;
        pk.x = pack2bf(v[0], v[1]);
        pk.y = pack2bf(v[2], v[3]);
        *(uint2*)&obase[(size_t)q * 576 + k0] = pk;
    }
}

// ---------------- LayerNorm over D=200; 4 rows per 256-thr block (one wave/row) ----------
__global__ __launch_bounds__(256) void ln_kernel(const float* __restrict__ in,
                                                 const float* __restrict__ g,
                                                 const float* __restrict__ b,
                                                 short* __restrict__ out) {
    int row = blockIdx.x * 4 + (threadIdx.x >> 6);
    int lane = threadIdx.x & 63;
    const float* x = in + (size_t)row * 200;
    float v[4];
    float s = 0.f;
#pragma unroll
    for (int i = 0; i < 4; i++) {
        int d = lane + i * 64;
        v[i] = (d < 200) ? x[d] : 0.f;
        s += v[i];
    }
#pragma unroll
    for (int o = 32; o; o >>= 1) s += __shfl_xor(s, o);
    float mean = s * (1.f / 200.f);
    float s2 = 0.f;
#pragma unroll
    for (int i = 0; i < 4; i++) {
        int d = lane + i * 64;
        float dv = (d < 200) ? (v[i] - mean) : 0.f;
        s2 += dv * dv;
    }
#pragma unroll
    for (int o = 32; o; o >>= 1) s2 += __shfl_xor(s2, o);
    float rstd = rsqrtf(s2 * (1.f / 200.f) + 1e-6f);
#pragma unroll
    for (int i = 0; i < 4; i++) {
        int d = lane + i * 64;
        float val = (d < 200) ? (v[i] - mean) * rstd * g[d] + b[d] : 0.f;
        out[(size_t)row * 256 + d] = f2bf(val);
    }
}

// ---------------- bf16 MFMA GEMM, double-buffered K-loop ----------------
// BM x BN block tile, BK=64, 4 waves 2x2. Counted vmcnt (never 0 mid-loop).
// EPI 0: Cf = acc (fp32)
// EPI 1: Cf = res + gamma[n]*(acc+bias[n])
// EPI 2: Cb = bf16(gelu(acc+bias[n])), zero pad cols N..NPout
// EPI 3: qkv scatter -> Qb[b][h][576][32] (scaled), Kb same, Vt[b][h][32][576]
template <int EPI, int BM, int BN>
__global__ __launch_bounds__(256) void gemm_bf(const short* __restrict__ A,
                                               const short* __restrict__ W,
                                               float* __restrict__ Cf,
                                               short* __restrict__ Cb,
                                               const float* __restrict__ res,
                                               const float* __restrict__ bias,
                                               const float* __restrict__ gamma,
                                               int M, int N, int KP, int ldc, int NPout,
                                               short* __restrict__ Qb = nullptr,
                                               short* __restrict__ Kb = nullptr,
                                               short* __restrict__ Vt = nullptr) {
    constexpr int WM = BM / 2, WN = BN / 2;
    constexpr int AM = WM / 16, BNr = WN / 16;
    constexpr int LOADS = (BM + BN) / 32;   // gloads per thread per k-step
    __shared__ __align__(16) short Ss[2][(BM + BN) * 64];

    const int tid = threadIdx.x;
    const int w = tid >> 6, l = tid & 63;
    const int wm = (w >> 1) * WM, wn = (w & 1) * WN;
    const int bm = blockIdx.y * BM, bn = blockIdx.x * BN;

    f32x4 acc[AM][BNr] = {};

    auto stage = [&](int buf, int k0) {
#pragma unroll
        for (int it = 0; it < LOADS; it++) {
            int lin = it * 256 + tid;
            int row = lin >> 3, slot = lin & 7;
            int srcslot = slot ^ (row & 7);
            const short* g;
            if (it * 32 < BM) {
                g = A + (size_t)(bm + row) * KP + k0 + srcslot * 8;
            } else {
                g = W + (size_t)(bn + row - BM) * KP + k0 + srcslot * 8;
            }
            gload_lds16(g, (char*)Ss[buf] + lin * 16);
        }
    };

    const int nk = KP >> 6;
    stage(0, 0);
    int cur = 0;
    for (int kstep = 0; kstep < nk; kstep++) {
        if (kstep + 1 < nk) {
            stage(cur ^ 1, (kstep + 1) << 6);
            if constexpr (LOADS == 6) asm volatile("s_waitcnt vmcnt(6)" ::: "memory");
            else                      asm volatile("s_waitcnt vmcnt(4)" ::: "memory");
        } else {
            asm volatile("s_waitcnt vmcnt(0)" ::: "memory");
        }
        __builtin_amdgcn_s_barrier();

        const char* Sc = (const char*)Ss[cur];
#pragma unroll
        for (int kk = 0; kk < 2; kk++) {
            const int kbyte = kk * 64 + (l >> 4) * 16;
            bf16x8 af[AM], bfr[BNr];
#pragma unroll
            for (int i = 0; i < AM; i++) {
                int r = wm + i * 16 + (l & 15);
                af[i] = *(const bf16x8*)(Sc + r * 128 + (kbyte ^ ((r & 7) << 4)));
            }
#pragma unroll
            for (int j = 0; j < BNr; j++) {
                int r = BM + wn + j * 16 + (l & 15);
                bfr[j] = *(const bf16x8*)(Sc + r * 128 + (kbyte ^ ((r & 7) << 4)));
            }
#pragma unroll
            for (int i = 0; i < AM; i++)
#pragma unroll
                for (int j = 0; j < BNr; j++)
                    acc[i][j] = __builtin_amdgcn_mfma_f32_16x16x32_bf16(af[i], bfr[j], acc[i][j], 0, 0, 0);
        }
        __builtin_amdgcn_s_barrier();  // all waves done reading Ss[cur] before overwrite
        cur ^= 1;
    }

    const int col0 = bn + wn + (l & 15);
    const int rbase = (l >> 4) * 4;
#pragma unroll
    for (int i = 0; i < AM; i++) {
#pragma unroll
        for (int r = 0; r < 4; r++) {
            int gm = bm + wm + i * 16 + rbase + r;
            if (gm >= M) continue;
#pragma unroll
            for (int j = 0; j < BNr; j++) {
                int gn = col0 + j * 16;
                float v = acc[i][j][r];
                if (EPI == 0) {
                    if (gn < N) Cf[(size_t)gm * ldc + gn] = v;
                } else if (EPI == 1) {
                    if (gn < N) Cf[(size_t)gm * ldc + gn] =
                        res[(size_t)gm * ldc + gn] + gamma[gn] * (v + bias[gn]);
                } else if (EPI == 2) {
                    if (gn < NPout)
                        Cb[(size_t)gm * ldc + gn] = (gn < N) ? f2bf(gelu_exact(v + bias[gn])) : (short)0;
                } else {  // EPI 3: qkv scatter
                    if (gn < 600) {
                        int bb2 = gm / 513, n = gm - bb2 * 513;
                        if (gn < 200) {
                            int hq = gn / 20, dq = gn - hq * 20;
                            Qb[((size_t)(bb2 * 10 + hq) * 576 + n) * 32 + dq] =
                                f2bf(v * 0.22360679774997896f);
                        } else if (gn < 400) {
                            int gk = gn - 200, hk = gk / 20, dk = gk - hk * 20;
                            Kb[((size_t)(bb2 * 10 + hk) * 576 + n) * 32 + dk] = f2bf(v);
                        } else {
                            int gv = gn - 400, hv = gv / 20, dv2 = gv - hv * 20;
                            Vt[((size_t)(bb2 * 10 + hv) * 32 + dv2) * 576 + n] = f2bf(v);
                        }
                    }
                }
            }
        }
    }
}

// ---------------- MFMA flash attention: dbuf K/V staging, bias direct-to-register -------
// Bias registers are loaded BEFORE the K/V prefetch each tile (older in vmcnt FIFO), so
// the counted vmcnt(2) both guarantees bias ready and keeps the prefetch pair in flight.
// LDS ~26 KB -> ~6 blocks/CU.
__global__ __launch_bounds__(256) void attn_mfma2(const short* __restrict__ Qb,
                                                  const short* __restrict__ Kb,
                                                  const short* __restrict__ Vt,
                                                  const short* __restrict__ biasb,
                                                  short* __restrict__ ob) {
    __shared__ __align__(16) short Klds[2][64 * 32];
    __shared__ __align__(16) short Vlds[2][32 * 64];
    __shared__ __align__(16) short Pl[4 * 16 * 72];

    const int orig = blockIdx.x;
    const int wg = (orig & 7) * 90 + (orig >> 3);   // XCD-chunked bijection (720 = 8*90)
    const int hh = wg / 72;
    const int rem = wg % 72;
    const int qt = rem >> 3, b = rem & 7;

    const int t = threadIdx.x, wave = t >> 6, l = t & 63;
    const int lq = l & 15, hi = l >> 4;
    const int n = qt * 64 + wave * 16 + lq;
    const int nc = min(n, 512);

    const size_t bh = (size_t)(b * 10 + hh);
    const short* Kbase = Kb + bh * 576 * 32;
    const short* Vbase = Vt + bh * 32 * 576;
    const short* Brow  = biasb + ((size_t)hh * 513 + nc) * 576;  // per-lane bias row

    bf16x8 qf = *(const bf16x8*)&Qb[(bh * 576 + nc) * 32 + hi * 8];

    const int krow = t >> 2, kch = t & 3;
    const short* ksrc = Kbase + (size_t)krow * 32 + (kch ^ ((krow >> 2) & 3)) * 8;
    const int vrow = t >> 3, vch = t & 7;
    const short* vsrc = Vbase + (size_t)vrow * 576 + (vch ^ (vrow & 7)) * 8;

    float mrun = -1e30f, lsum = 0.f;
    f32x4 oacc0 = {}, oacc1 = {};
    const f32x4 zero4 = {};

    // prologue: stage tile 0 into buffer 0
    gload_lds16(ksrc, (char*)Klds[0] + t * 16);
    gload_lds16(vsrc, (char*)Vlds[0] + t * 16);

    int cur = 0;
    for (int kt = 0; kt < 9; kt++) {
        const int koff = kt * 64;

        // bias for THIS tile -> registers (issued before prefetch: older in vmcnt order)
        uint2 bl[4];
#pragma unroll
        for (int c = 0; c < 4; c++)
            bl[c] = *(const uint2*)&Brow[koff + c * 16 + hi * 4];

        if (kt < 8) {
            const int knext = koff + 64;
            gload_lds16(ksrc + (size_t)knext * 32, (char*)Klds[cur ^ 1] + t * 16);
            gload_lds16(vsrc + knext, (char*)Vlds[cur ^ 1] + t * 16);
            asm volatile("s_waitcnt vmcnt(2)" ::: "memory");  // bias + this tile done
        } else {
            asm volatile("s_waitcnt vmcnt(0)" ::: "memory");
        }
        __builtin_amdgcn_s_barrier();

        const short* Kc = Klds[cur];
        const short* Vc = Vlds[cur];

        f32x4 s[4];
        __builtin_amdgcn_s_setprio(1);
#pragma unroll
        for (int c = 0; c < 4; c++) {
            int r = c * 16 + lq;
            bf16x8 kf = *(const bf16x8*)((const char*)Kc + r * 64 + ((hi ^ ((lq >> 2) & 3)) << 4));
            s[c] = __builtin_amdgcn_mfma_f32_16x16x32_bf16(kf, qf, zero4, 0, 0, 0);
        }
        __builtin_amdgcn_s_setprio(0);

        float sv[4][4];
        float tm = -1e30f;
#pragma unroll
        for (int c = 0; c < 4; c++) {
            float bv[4] = { bf2f((unsigned short)(bl[c].x & 0xFFFF)), bf2f((unsigned short)(bl[c].x >> 16)),
                            bf2f((unsigned short)(bl[c].y & 0xFFFF)), bf2f((unsigned short)(bl[c].y >> 16)) };
            int kglob = koff + c * 16 + hi * 4;
#pragma unroll
            for (int r = 0; r < 4; r++) {
                float val = s[c][r] + bv[r];
                if (kglob + r > 512) val = -1e30f;
                sv[c][r] = val;
                tm = fmaxf(tm, val);
            }
        }
        tm = fmaxf(tm, __shfl_xor(tm, 16));
        tm = fmaxf(tm, __shfl_xor(tm, 32));
        float mnew = fmaxf(mrun, tm);
        float resc = __expf(mrun - mnew);
        mrun = mnew;

        float ts = 0.f;
#pragma unroll
        for (int c = 0; c < 4; c++) {
            float p0 = __expf(sv[c][0] - mnew);
            float p1 = __expf(sv[c][1] - mnew);
            float p2 = __expf(sv[c][2] - mnew);
            float p3 = __expf(sv[c][3] - mnew);
            ts += (p0 + p1) + (p2 + p3);
            uint2 pk;
            pk.x = pack2bf(p0, p1);
            pk.y = pack2bf(p2, p3);
            *(uint2*)&Pl[wave * 1152 + lq * 72 + c * 16 + hi * 4] = pk;
        }
        ts += __shfl_xor(ts, 16);
        ts += __shfl_xor(ts, 32);
        lsum = lsum * resc + ts;
        oacc0 *= resc;
        oacc1 *= resc;

        __builtin_amdgcn_s_setprio(1);
#pragma unroll
        for (int kc = 0; kc < 2; kc++) {
            bf16x8 pf = *(const bf16x8*)&Pl[wave * 1152 + lq * 72 + kc * 32 + hi * 8];
            bf16x8 vf0 = *(const bf16x8*)((const char*)Vc + lq * 128 +
                                          (((kc * 4 + hi) ^ (lq & 7)) << 4));
            bf16x8 vf1 = *(const bf16x8*)((const char*)Vc + (16 + lq) * 128 +
                                          (((kc * 4 + hi) ^ (lq & 7)) << 4));
            oacc0 = __builtin_amdgcn_mfma_f32_16x16x32_bf16(vf0, pf, oacc0, 0, 0, 0);
            oacc1 = __builtin_amdgcn_mfma_f32_16x16x32_bf16(vf1, pf, oacc1, 0, 0, 0);
        }
        __builtin_amdgcn_s_setprio(0);

        __builtin_amdgcn_s_barrier();
        cur ^= 1;
    }

    if (n < 513) {
        float inv = 1.f / lsum;
        short* op = ob + (size_t)(b * 513 + n) * 256 + hh * 20;
        {
            uint2 pk;
            pk.x = pack2bf(oacc0[0] * inv, oacc0[1] * inv);
            pk.y = pack2bf(oacc0[2] * inv, oacc0[3] * inv);
            *(uint2*)&op[hi * 4] = pk;
        }
        if (hi == 0) {
            uint2 pk;
            pk.x = pack2bf(oacc1[0] * inv, oacc1[1] * inv);
            pk.y = pack2bf(oacc1[2] * inv, oacc1[3] * inv);
            *(uint2*)&op[16] = pk;
        }
    }
}

// ---------------- final: mean-pool patches -> LN -> head (200 -> 4) ----------------
__global__ __launch_bounds__(256) void final_kernel(const float* __restrict__ h,
                                                    const float* __restrict__ g,
                                                    const float* __restrict__ bb,
                                                    const float* __restrict__ hw,
                                                    const float* __restrict__ hb,
                                                    float* __restrict__ out) {
    __shared__ float pool[256];
    __shared__ float red[256];
    int b = blockIdx.x, t = threadIdx.x;
    float s = 0.f;
    if (t < 200) {
        const float* hp = h + b * 513 * 200 + 200 + t;
        for (int p = 0; p < 512; p++) s += hp[p * 200];
        s *= (1.f / 512.f);
    }
    pool[t] = (t < 200) ? s : 0.f;
    red[t] = pool[t];
    __syncthreads();
    for (int o = 128; o; o >>= 1) {
        if (t < o) red[t] += red[t + o];
        __syncthreads();
    }
    float mean = red[0] / 200.f;
    __syncthreads();
    float dv = (t < 200) ? (pool[t] - mean) : 0.f;
    red[t] = dv * dv;
    __syncthreads();
    for (int o = 128; o; o >>= 1) {
        if (t < o) red[t] += red[t + o];
        __syncthreads();
    }
    float var = red[0] / 200.f;
    float rstd = rsqrtf(var + 1e-6f);
    __syncthreads();
    if (t < 200) pool[t] = (pool[t] - mean) * rstd * g[t] + bb[t];
    __syncthreads();
    if (t < 4) {
        float acc = hb[t];
        for (int d2 = 0; d2 < 200; d2++) acc += pool[d2] * hw[t * 200 + d2];
        out[b * 4 + t] = acc;
    }
}

extern "C" void kernel_launch(void* const* d_in, const int* in_sizes, int n_in,
                              void* d_out, int out_size, void* d_ws, size_t ws_size,
                              hipStream_t stream) {
    const float* x        = (const float*)d_in[0];
    const float* conv1_w  = (const float*)d_in[1];
    const float* conv1_b  = (const float*)d_in[2];
    const float* gn1_g    = (const float*)d_in[3];
    const float* gn1_b    = (const float*)d_in[4];
    const float* conv2_w  = (const float*)d_in[5];
    const float* conv2_b  = (const float*)d_in[6];
    const float* gn2_g    = (const float*)d_in[7];
    const float* gn2_b    = (const float*)d_in[8];
    const float* conv3_w  = (const float*)d_in[9];
    const float* conv3_b  = (const float*)d_in[10];
    const float* gn3_g    = (const float*)d_in[11];
    const float* gn3_b    = (const float*)d_in[12];
    const float* cls_tok  = (const float*)d_in[13];
    const float* pos_emb  = (const float*)d_in[14];
    const float* time_emb = (const float*)d_in[15];
    const float* ln1_g    = (const float*)d_in[16];
    const float* ln1_b    = (const float*)d_in[17];
    const float* qkv_w    = (const float*)d_in[18];
    const float* rel_tab  = (const float*)d_in[19];
    const float* proj_w   = (const float*)d_in[20];
    const float* proj_b   = (const float*)d_in[21];
    const float* gamma1   = (const float*)d_in[22];
    const float* ln2_g    = (const float*)d_in[23];
    const float* ln2_b    = (const float*)d_in[24];
    const float* fc1_w    = (const float*)d_in[25];
    const float* fc1_b    = (const float*)d_in[26];
    const float* fc2_w    = (const float*)d_in[27];
    const float* fc2_b    = (const float*)d_in[28];
    const float* gamma2   = (const float*)d_in[29];
    const float* fcn_g    = (const float*)d_in[30];
    const float* fcn_b    = (const float*)d_in[31];
    const float* head_w   = (const float*)d_in[32];
    const float* head_b   = (const float*)d_in[33];
    const int*   rel_idx  = (const int*)d_in[34];

    // ---- workspace layout (bytes), total ~102 MB ----
    char* p = (char*)d_ws;
    float* h    = (float*)p; p += 3283200;          // 8*513*200 f32
    char* qreg = p;                                  // multi-phase region
    float* c1   = (float*)qreg;
    float* c2   = c1 + 819200;
    short* Qb   = (short*)qreg;                     // [8][10][576][32]
    short* Kb   = Qb + 1474560;
    short* Vt   = Kb + 1474560;                     // [8][10][32][576]
    short* mlp  = (short*)qreg;                     // [4104][832] (MLP phase)
    p += 9849600;
    short* y    = (short*)p; p += 2101248;          // 4104*256 bf16
    short* ob   = (short*)p; p += 2101248;          // 4104*256 bf16
    short* wqkv = (short*)p; p += 3686400;
    short* wproj= (short*)p; p += 1228800;
    short* wfc1 = (short*)p; p += 4915200;
    short* wfc2 = (short*)p; p += 3993600;
    short* biasb= (short*)p; p += 12 * 5909760;     // [12][10][513][576] bf16 = 70.9 MB
    float* stats= (float*)p;

    // ---- upfront precompute ----
    convpad_kernel<<<(7200 * 64 + 255) / 256, 256, 0, stream>>>(qkv_w, wqkv, 7200, 200, 256);
    convpad_kernel<<<(2400 * 64 + 255) / 256, 256, 0, stream>>>(proj_w, wproj, 2400, 200, 256);
    convpad_kernel<<<(9600 * 64 + 255) / 256, 256, 0, stream>>>(fc1_w, wfc1, 9600, 200, 256);
    convpad_kernel<<<(2400 * 208 + 255) / 256, 256, 0, stream>>>(fc2_w, wfc2, 2400, 800, 832);
    bias_lds_kernel<<<dim3(9, 10, 12), 256, 0, stream>>>(rel_tab, rel_idx, biasb);
    hipMemsetAsync(ob, 0, 2101248, stream);

    // ---- patch embed ----
    conv1_kernel<<<3200, 256, 0, stream>>>(x, conv1_w, conv1_b, c1);
    gn_stats_kernel<<<32, 256, 0, stream>>>(c1, stats);
    gn_apply_kernel<<<3200, 256, 0, stream>>>(c1, stats, gn1_g, gn1_b);
    conv3x1_kernel<<<3200, 256, 0, stream>>>(c1, conv2_w, conv2_b, c2);
    gn_stats_kernel<<<32, 256, 0, stream>>>(c2, stats);
    gn_apply_kernel<<<3200, 256, 0, stream>>>(c2, stats, gn2_g, gn2_b);
    conv3x1_kernel<<<3200, 256, 0, stream>>>(c2, conv3_w, conv3_b, c1);
    gn_stats_kernel<<<32, 256, 0, stream>>>(c1, stats);
    gn_apply_kernel<<<3200, 256, 0, stream>>>(c1, stats, gn3_g, gn3_b);
    embed_kernel<<<(820800 + 255) / 256, 256, 0, stream>>>(c1, cls_tok, pos_emb, time_emb, h);

    hipMemsetAsync(Qb, 0, 3 * 1474560 * 2, stream);  // zero QKV pad regions (post conv phase)

    // ---- transformer layers ----
    for (int d = 0; d < 12; d++) {
        ln_kernel<<<1026, 256, 0, stream>>>(h, ln1_g + d * 200, ln1_b + d * 200, y);
        gemm_bf<3, 64, 64><<<dim3(10, 65), 256, 0, stream>>>(y, wqkv + d * 153600,
                                                             nullptr, nullptr, nullptr, nullptr, nullptr,
                                                             4104, 600, 256, 0, 0, Qb, Kb, Vt);
        attn_mfma2<<<720, 256, 0, stream>>>(Qb, Kb, Vt, biasb + (size_t)d * 2954880, ob);
        gemm_bf<1, 64, 64><<<dim3(4, 65), 256, 0, stream>>>(ob, wproj + d * 51200, h, nullptr,
                                                            h, proj_b + d * 200, gamma1 + d * 200,
                                                            4104, 200, 256, 200, 0);
        ln_kernel<<<1026, 256, 0, stream>>>(h, ln2_g + d * 200, ln2_b + d * 200, y);
        gemm_bf<2, 64, 64><<<dim3(13, 65), 256, 0, stream>>>(y, wfc1 + d * 204800, nullptr, mlp,
                                                             nullptr, fc1_b + d * 800, nullptr,
                                                             4104, 800, 256, 832, 832);
        gemm_bf<1, 64, 64><<<dim3(4, 65), 256, 0, stream>>>(mlp, wfc2 + d * 166400, h, nullptr,
                                                            h, fc2_b + d * 200, gamma2 + d * 200,
                                                            4104, 200, 832, 200, 0);
    }

    // ---- pool + head ----
    final_kernel<<<8, 256, 0, stream>>>(h, fcn_g, fcn_b, head_w, head_b, (float*)d_out);
}